// Round 5
// baseline (663.916 us; speedup 1.0000x reference)
//
#include <hip/hip_runtime.h>

#define NN 50000
#define NE 800000
#define EH (NE + NN)   // 850000 edges incl. self-loops
#define HD 128
#define NB 196         // ceil(NN/256)
#define NCH 8          // column chunks (one per XCD)
#define CPW 16         // cols per chunk
#define PSTR (NN * CPW)  // floats per panel = 800000

// ---------------- degree / CSR build ----------------
__global__ void k_init_deg(int* __restrict__ deg) {
  int i = blockIdx.x * 256 + threadIdx.x;
  if (i < NN) deg[i] = 1;   // self-loop contributes 1
}

__global__ void k_count(const int* __restrict__ dst, int* __restrict__ deg) {
  int e = blockIdx.x * 256 + threadIdx.x;
  if (e < NE) atomicAdd(&deg[dst[e]], 1);
}

// stage 1: per-block sums of deg
__global__ __launch_bounds__(256) void k_partial(const int* __restrict__ deg,
                                                 int* __restrict__ partial) {
  int i = blockIdx.x * 256 + threadIdx.x;
  int v = (i < NN) ? deg[i] : 0;
  #pragma unroll
  for (int off = 32; off >= 1; off >>= 1) v += __shfl_down(v, off);
  __shared__ int ws[4];
  if ((threadIdx.x & 63) == 0) ws[threadIdx.x >> 6] = v;
  __syncthreads();
  if (threadIdx.x == 0) partial[blockIdx.x] = ws[0] + ws[1] + ws[2] + ws[3];
}

// stage 2: exclusive scan of the 196 partials
__global__ __launch_bounds__(256) void k_scanp(int* __restrict__ partial) {
  __shared__ int lds[256];
  int t = threadIdx.x;
  int v = (t < NB) ? partial[t] : 0;
  lds[t] = v;
  __syncthreads();
  #pragma unroll
  for (int off = 1; off < 256; off <<= 1) {
    int u = (t >= off) ? lds[t - off] : 0;
    __syncthreads();
    lds[t] += u;
    __syncthreads();
  }
  if (t < NB) partial[t] = lds[t] - v;   // exclusive
}

// stage 3: row_start/cursor + fused dis=rsqrt(deg)
__global__ __launch_bounds__(256) void k_scatter(const int* __restrict__ deg,
                                                 const int* __restrict__ partial,
                                                 int* __restrict__ row_start,
                                                 int* __restrict__ cursor,
                                                 float* __restrict__ dis) {
  __shared__ int lds[256];
  int t = threadIdx.x;
  int i = blockIdx.x * 256 + t;
  int v = (i < NN) ? deg[i] : 0;
  lds[t] = v;
  __syncthreads();
  #pragma unroll
  for (int off = 1; off < 256; off <<= 1) {
    int u = (t >= off) ? lds[t - off] : 0;
    __syncthreads();
    lds[t] += u;
    __syncthreads();
  }
  int ex = lds[t] - v + partial[blockIdx.x];
  if (i < NN) {
    row_start[i] = ex;
    cursor[i] = ex;
    dis[i] = rsqrtf((float)v);   // deg >= 1 always
    if (i == NN - 1) row_start[NN] = ex + v;
  }
}

__global__ void k_fill(const int* __restrict__ src, const int* __restrict__ dst,
                       int* __restrict__ cursor, int* __restrict__ csr_src) {
  int e = blockIdx.x * 256 + threadIdx.x;
  if (e >= EH) return;
  int s, d;
  if (e < NE) { s = src[e]; d = dst[e]; }
  else        { s = e - NE; d = s; }          // self-loop
  int pos = atomicAdd(&cursor[d], 1);
  csr_src[pos] = s;
}

// ---------------- degree counting-sort: perm = nodes ordered by degree ----------
__global__ void k_hist(const int* __restrict__ deg, int* __restrict__ hist) {
  int i = blockIdx.x * 256 + threadIdx.x;
  if (i < NN) {
    int b = deg[i]; if (b > 1023) b = 1023;
    atomicAdd(&hist[b], 1);
  }
}

__global__ __launch_bounds__(1024) void k_scanh(int* __restrict__ hist) {
  __shared__ int lds[1024];
  int t = threadIdx.x;
  int v = hist[t];
  lds[t] = v;
  __syncthreads();
  #pragma unroll
  for (int off = 1; off < 1024; off <<= 1) {
    int u = (t >= off) ? lds[t - off] : 0;
    __syncthreads();
    lds[t] += u;
    __syncthreads();
  }
  hist[t] = lds[t] - v;   // exclusive bin offsets (consumed as cursors by k_perm)
}

__global__ void k_perm(const int* __restrict__ deg, int* __restrict__ hist,
                       int* __restrict__ perm) {
  int i = blockIdx.x * 256 + threadIdx.x;
  if (i < NN) {
    int b = deg[i]; if (b > 1023) b = 1023;
    int pos = atomicAdd(&hist[b], 1);
    perm[pos] = i;
  }
}

// ---------------- dense GEMM: C = dis[row] * (A[NN,128] @ W[128,128]) -------------
// Output in chunk-panel layout: panel p holds cols [16p,16p+16), contiguous 3.2 MB.
#define GR 128
__global__ __launch_bounds__(256, 1) void k_gemm(const float* __restrict__ A,
                                                 const float* __restrict__ W,
                                                 const float* __restrict__ dis,
                                                 float* __restrict__ C) {
  __shared__ float As[GR][HD + 4];
  __shared__ float Ws[HD * HD];
  const int tid = threadIdx.x;
  const int r0 = blockIdx.x * GR;
  #pragma unroll
  for (int m = 0; m < 16; ++m) {
    int f = tid + m * 256;
    ((float4*)Ws)[f] = ((const float4*)W)[f];
  }
  #pragma unroll
  for (int m = 0; m < 16; ++m) {
    int f = tid + m * 256;
    int r = f >> 5, c4 = f & 31;
    int gr_ = r0 + r;
    float4 v = make_float4(0.f, 0.f, 0.f, 0.f);
    if (gr_ < NN) v = ((const float4*)A)[gr_ * 32 + c4];
    *(float4*)&As[r][c4 * 4] = v;
  }
  __syncthreads();
  const int tg = tid >> 4;
  const int tc = tid & 15;
  const int cc = tc * 4;
  float acc[8][8];
  #pragma unroll
  for (int j = 0; j < 8; ++j)
    #pragma unroll
    for (int c = 0; c < 8; ++c) acc[j][c] = 0.f;

  for (int k = 0; k < HD; k += 4) {
    float4 a[8];
    #pragma unroll
    for (int j = 0; j < 8; ++j) a[j] = *(const float4*)&As[tg + 16 * j][k];
    #pragma unroll
    for (int kk = 0; kk < 4; ++kk) {
      float4 w0 = *(const float4*)&Ws[(k + kk) * HD + cc];
      float4 w1 = *(const float4*)&Ws[(k + kk) * HD + cc + 64];
      #pragma unroll
      for (int j = 0; j < 8; ++j) {
        float av = (kk == 0) ? a[j].x : (kk == 1) ? a[j].y : (kk == 2) ? a[j].z : a[j].w;
        acc[j][0] += av * w0.x; acc[j][1] += av * w0.y;
        acc[j][2] += av * w0.z; acc[j][3] += av * w0.w;
        acc[j][4] += av * w1.x; acc[j][5] += av * w1.y;
        acc[j][6] += av * w1.z; acc[j][7] += av * w1.w;
      }
    }
  }
  const int p0 = cc >> 4;
  const int pc = cc & 15;
  #pragma unroll
  for (int j = 0; j < 8; ++j) {
    int row = r0 + tg + 16 * j;
    if (row < NN) {
      const float dsc = dis[row];
      *(float4*)&C[p0 * PSTR + row * CPW + pc] =
          make_float4(acc[j][0] * dsc, acc[j][1] * dsc, acc[j][2] * dsc, acc[j][3] * dsc);
      *(float4*)&C[(p0 + 4) * PSTR + row * CPW + pc] =
          make_float4(acc[j][4] * dsc, acc[j][5] * dsc, acc[j][6] * dsc, acc[j][7] * dsc);
    }
  }
}

// ---------------- CSR gather-aggregate (degree-sorted, float4, no reduction) ------
// thread = (node, 4 cols). 64 nodes/block via perm (degree-adjacent -> a wave's 16
// nodes have ~equal degree -> negligible divergence). chunk = bid&7 -> XCD-pinned
// 3.2 MB panel. No per-edge weight (folded into GEMM), no mask, no shuffle.
__global__ __launch_bounds__(256) void k_agg(const float* __restrict__ Tpanels,
                                             const float* __restrict__ dis,
                                             const int* __restrict__ row_start,
                                             const int* __restrict__ csr_src,
                                             const int* __restrict__ perm,
                                             const float* __restrict__ bias,
                                             float* __restrict__ out) {
  const int tid = threadIdx.x;
  const int chunk = blockIdx.x & (NCH - 1);
  const int idx = (blockIdx.x >> 3) * 64 + (tid >> 2);
  if (idx >= NN) return;
  const int n = perm[idx];
  const int c4 = tid & 3;
  const float4* __restrict__ P4 = (const float4*)(Tpanels + chunk * PSTR);

  const int rs = row_start[n], re = row_start[n + 1];
  float4 a0 = make_float4(0.f, 0.f, 0.f, 0.f);
  float4 a1 = make_float4(0.f, 0.f, 0.f, 0.f);
  int j = rs;
  for (; j + 1 < re; j += 2) {
    int s0 = csr_src[j], s1 = csr_src[j + 1];
    float4 v0 = P4[s0 * 4 + c4];
    float4 v1 = P4[s1 * 4 + c4];
    a0.x += v0.x; a0.y += v0.y; a0.z += v0.z; a0.w += v0.w;
    a1.x += v1.x; a1.y += v1.y; a1.z += v1.z; a1.w += v1.w;
  }
  if (j < re) {
    int s = csr_src[j];
    float4 v = P4[s * 4 + c4];
    a0.x += v.x; a0.y += v.y; a0.z += v.z; a0.w += v.w;
  }
  const float dn = dis[n];
  const float4 bb = ((const float4*)bias)[chunk * 4 + c4];
  float4 r;
  r.x = (a0.x + a1.x) * dn + bb.x;
  r.y = (a0.y + a1.y) * dn + bb.y;
  r.z = (a0.z + a1.z) * dn + bb.z;
  r.w = (a0.w + a1.w) * dn + bb.w;
  r.x = (r.x >= 0.f) ? r.x : 0.01f * r.x;
  r.y = (r.y >= 0.f) ? r.y : 0.01f * r.y;
  r.z = (r.z >= 0.f) ? r.z : 0.01f * r.z;
  r.w = (r.w >= 0.f) ? r.w : 0.01f * r.w;
  ((float4*)out)[n * (HD / 4) + chunk * 4 + c4] = r;
}

extern "C" void kernel_launch(void* const* d_in, const int* in_sizes, int n_in,
                              void* d_out, int out_size, void* d_ws, size_t ws_size,
                              hipStream_t stream) {
  const float* x  = (const float*)d_in[0];
  const int*   ei = (const int*)d_in[1];
  const float* W0 = (const float*)d_in[2];
  const float* b0 = (const float*)d_in[3];
  const float* W1 = (const float*)d_in[4];
  const float* b1 = (const float*)d_in[5];
  float* out = (float*)d_out;
  const int* src = ei;        // edge_index[0] = message source
  const int* dst = ei + NE;   // edge_index[1] = aggregation target

  char* p = (char*)d_ws;
  int*   deg       = (int*)p;    p += 50048 * 4;
  float* dis       = (float*)p;  p += 50048 * 4;
  int*   row_start = (int*)p;    p += 50052 * 4;
  int*   cursor    = (int*)p;    p += 50048 * 4;
  int*   partial   = (int*)p;    p += 256 * 4;
  int*   hist      = (int*)p;    p += 1024 * 4;
  int*   perm      = (int*)p;    p += 50048 * 4;
  int*   csr       = (int*)p;    p += 850048 * 4;
  float* bufA      = (float*)p;  // 6,400,000 floats (25.6 MB) in 8 panels

  // graph build (once, reused by both layers)
  k_init_deg<<<196, 256, 0, stream>>>(deg);
  k_count<<<3125, 256, 0, stream>>>(dst, deg);
  k_partial<<<NB, 256, 0, stream>>>(deg, partial);
  k_scanp<<<1, 256, 0, stream>>>(partial);
  k_scatter<<<NB, 256, 0, stream>>>(deg, partial, row_start, cursor, dis);
  k_fill<<<(EH + 255) / 256, 256, 0, stream>>>(src, dst, cursor, csr);
  // degree counting-sort -> perm
  hipMemsetAsync(hist, 0, 1024 * 4, stream);
  k_hist<<<196, 256, 0, stream>>>(deg, hist);
  k_scanh<<<1, 1024, 0, stream>>>(hist);
  k_perm<<<196, 256, 0, stream>>>(deg, hist, perm);

  const int AGG_GRID = NCH * ((NN + 63) / 64);   // 8 * 782 = 6256 blocks
  // layer 1
  k_gemm<<<(NN + GR - 1) / GR, 256, 0, stream>>>(x, W0, dis, bufA);
  k_agg<<<AGG_GRID, 256, 0, stream>>>(bufA, dis, row_start, csr, perm, b0, out);
  // layer 2
  k_gemm<<<(NN + GR - 1) / GR, 256, 0, stream>>>(out, W1, dis, bufA);
  k_agg<<<AGG_GRID, 256, 0, stream>>>(bufA, dis, row_start, csr, perm, b1, out);
}

// Round 6
// 370.332 us; speedup vs baseline: 1.7928x; 1.7928x over previous
//
#include <hip/hip_runtime.h>

#define NN 50000
#define NE 800000
#define EH (NE + NN)   // 850000 edges incl. self-loops
#define HD 128
#define NB 196         // ceil(NN/256)
#define NCH 8          // column chunks (one per XCD)
#define CPW 16         // cols per chunk
#define PSTR (NN * CPW)  // floats per panel = 800000
#define NBINS 1024
#define NSUB 64        // sub-bins to decontend atomics
#define NH2 (NBINS * NSUB)   // 65536

// ---------------- graph build ----------------
__global__ void k_init_deg(int* __restrict__ deg) {
  int i = blockIdx.x * 256 + threadIdx.x;
  if (i < NN) deg[i] = 1;   // self-loop contributes 1
}

__global__ void k_count(const int* __restrict__ dst, int* __restrict__ deg) {
  int e = blockIdx.x * 256 + threadIdx.x;
  if (e < NE) atomicAdd(&deg[dst[e]], 1);
}

// generic per-block sums (256/block)
__global__ __launch_bounds__(256) void k_blocksum(const int* __restrict__ in,
                                                  int* __restrict__ partial, int nelem) {
  int i = blockIdx.x * 256 + threadIdx.x;
  int v = (i < nelem) ? in[i] : 0;
  #pragma unroll
  for (int off = 32; off >= 1; off >>= 1) v += __shfl_down(v, off);
  __shared__ int ws[4];
  if ((threadIdx.x & 63) == 0) ws[threadIdx.x >> 6] = v;
  __syncthreads();
  if (threadIdx.x == 0) partial[blockIdx.x] = ws[0] + ws[1] + ws[2] + ws[3];
}

// generic small exclusive scan (n <= 256), one block of 256
__global__ __launch_bounds__(256) void k_scanp(int* __restrict__ data, int n) {
  __shared__ int lds[256];
  int t = threadIdx.x;
  int v = (t < n) ? data[t] : 0;
  lds[t] = v;
  __syncthreads();
  #pragma unroll
  for (int off = 1; off < 256; off <<= 1) {
    int u = (t >= off) ? lds[t - off] : 0;
    __syncthreads();
    lds[t] += u;
    __syncthreads();
  }
  if (t < n) data[t] = lds[t] - v;   // exclusive
}

// row_start/cursor + fused dis = rsqrt(deg)
__global__ __launch_bounds__(256) void k_scatter(const int* __restrict__ deg,
                                                 const int* __restrict__ partial,
                                                 int* __restrict__ row_start,
                                                 int* __restrict__ cursor,
                                                 float* __restrict__ dis) {
  __shared__ int lds[256];
  int t = threadIdx.x;
  int i = blockIdx.x * 256 + t;
  int v = (i < NN) ? deg[i] : 0;
  lds[t] = v;
  __syncthreads();
  #pragma unroll
  for (int off = 1; off < 256; off <<= 1) {
    int u = (t >= off) ? lds[t - off] : 0;
    __syncthreads();
    lds[t] += u;
    __syncthreads();
  }
  int ex = lds[t] - v + partial[blockIdx.x];
  if (i < NN) {
    row_start[i] = ex;
    cursor[i] = ex;
    dis[i] = rsqrtf((float)v);   // deg >= 1 always
    if (i == NN - 1) row_start[NN] = ex + v;
  }
}

__global__ void k_fill(const int* __restrict__ src, const int* __restrict__ dst,
                       int* __restrict__ cursor, int* __restrict__ csr_src) {
  int e = blockIdx.x * 256 + threadIdx.x;
  if (e >= EH) return;
  int s, d;
  if (e < NE) { s = src[e]; d = dst[e]; }
  else        { s = e - NE; d = s; }          // self-loop
  int pos = atomicAdd(&cursor[d], 1);
  csr_src[pos] = s;
}

// ------------- degree counting-sort (2-level bins: ~64x less atomic contention) ----
__global__ void k_hist2(const int* __restrict__ deg, int* __restrict__ h) {
  int i = blockIdx.x * 256 + threadIdx.x;
  if (i < NN) {
    int b = deg[i]; if (b > NBINS - 1) b = NBINS - 1;
    atomicAdd(&h[b * NSUB + (i & (NSUB - 1))], 1);
  }
}

// generic in-place exclusive scan apply (data <- excl_scan(data) using block partials)
__global__ __launch_bounds__(256) void k_excl(int* __restrict__ data,
                                              const int* __restrict__ partial, int nelem) {
  __shared__ int lds[256];
  int t = threadIdx.x;
  int i = blockIdx.x * 256 + t;
  int v = (i < nelem) ? data[i] : 0;
  lds[t] = v;
  __syncthreads();
  #pragma unroll
  for (int off = 1; off < 256; off <<= 1) {
    int u = (t >= off) ? lds[t - off] : 0;
    __syncthreads();
    lds[t] += u;
    __syncthreads();
  }
  if (i < nelem) data[i] = lds[t] - v + partial[blockIdx.x];
}

__global__ void k_perm2(const int* __restrict__ deg, int* __restrict__ h,
                        int* __restrict__ perm) {
  int i = blockIdx.x * 256 + threadIdx.x;
  if (i < NN) {
    int b = deg[i]; if (b > NBINS - 1) b = NBINS - 1;
    int pos = atomicAdd(&h[b * NSUB + (i & (NSUB - 1))], 1);
    perm[pos] = i;
  }
}

// ---------------- dense GEMM: C = dis[row] * (A[NN,128] @ W[128,128]) -------------
// Output in chunk-panel layout: panel p holds cols [16p,16p+16), contiguous 3.2 MB.
#define GR 128
__global__ __launch_bounds__(256, 1) void k_gemm(const float* __restrict__ A,
                                                 const float* __restrict__ W,
                                                 const float* __restrict__ dis,
                                                 float* __restrict__ C) {
  __shared__ float As[GR][HD + 4];
  __shared__ float Ws[HD * HD];
  const int tid = threadIdx.x;
  const int r0 = blockIdx.x * GR;
  #pragma unroll
  for (int m = 0; m < 16; ++m) {
    int f = tid + m * 256;
    ((float4*)Ws)[f] = ((const float4*)W)[f];
  }
  #pragma unroll
  for (int m = 0; m < 16; ++m) {
    int f = tid + m * 256;
    int r = f >> 5, c4 = f & 31;
    int gr_ = r0 + r;
    float4 v = make_float4(0.f, 0.f, 0.f, 0.f);
    if (gr_ < NN) v = ((const float4*)A)[gr_ * 32 + c4];
    *(float4*)&As[r][c4 * 4] = v;
  }
  __syncthreads();
  const int tg = tid >> 4;
  const int tc = tid & 15;
  const int cc = tc * 4;
  float acc[8][8];
  #pragma unroll
  for (int j = 0; j < 8; ++j)
    #pragma unroll
    for (int c = 0; c < 8; ++c) acc[j][c] = 0.f;

  for (int k = 0; k < HD; k += 4) {
    float4 a[8];
    #pragma unroll
    for (int j = 0; j < 8; ++j) a[j] = *(const float4*)&As[tg + 16 * j][k];
    #pragma unroll
    for (int kk = 0; kk < 4; ++kk) {
      float4 w0 = *(const float4*)&Ws[(k + kk) * HD + cc];
      float4 w1 = *(const float4*)&Ws[(k + kk) * HD + cc + 64];
      #pragma unroll
      for (int j = 0; j < 8; ++j) {
        float av = (kk == 0) ? a[j].x : (kk == 1) ? a[j].y : (kk == 2) ? a[j].z : a[j].w;
        acc[j][0] += av * w0.x; acc[j][1] += av * w0.y;
        acc[j][2] += av * w0.z; acc[j][3] += av * w0.w;
        acc[j][4] += av * w1.x; acc[j][5] += av * w1.y;
        acc[j][6] += av * w1.z; acc[j][7] += av * w1.w;
      }
    }
  }
  const int p0 = cc >> 4;
  const int pc = cc & 15;
  #pragma unroll
  for (int j = 0; j < 8; ++j) {
    int row = r0 + tg + 16 * j;
    if (row < NN) {
      const float dsc = dis[row];
      *(float4*)&C[p0 * PSTR + row * CPW + pc] =
          make_float4(acc[j][0] * dsc, acc[j][1] * dsc, acc[j][2] * dsc, acc[j][3] * dsc);
      *(float4*)&C[(p0 + 4) * PSTR + row * CPW + pc] =
          make_float4(acc[j][4] * dsc, acc[j][5] * dsc, acc[j][6] * dsc, acc[j][7] * dsc);
    }
  }
}

// ---------------- CSR gather-aggregate (sorted, float4, 8-deep MLP) ----------------
// thread = (node, 4 cols). Wave = 16 degree-adjacent nodes (perm) -> uniform trips.
// 8 csr indices prefetched, then 8 independent 16B gathers in flight per thread.
__global__ __launch_bounds__(256) void k_agg(const float* __restrict__ Tpanels,
                                             const float* __restrict__ dis,
                                             const int* __restrict__ row_start,
                                             const int* __restrict__ csr_src,
                                             const int* __restrict__ perm,
                                             const float* __restrict__ bias,
                                             float* __restrict__ out) {
  const int tid = threadIdx.x;
  const int chunk = blockIdx.x & (NCH - 1);
  const int idx = (blockIdx.x >> 3) * 64 + (tid >> 2);
  if (idx >= NN) return;
  const int n = perm[idx];
  const int c4 = tid & 3;
  const float4* __restrict__ P4 = (const float4*)(Tpanels + chunk * PSTR);

  const int rs = row_start[n], re = row_start[n + 1];
  float4 a0 = make_float4(0.f, 0.f, 0.f, 0.f);
  float4 a1 = make_float4(0.f, 0.f, 0.f, 0.f);
  int j = rs;
  for (; j + 8 <= re; j += 8) {
    int s0 = csr_src[j],     s1 = csr_src[j + 1], s2 = csr_src[j + 2], s3 = csr_src[j + 3];
    int s4 = csr_src[j + 4], s5 = csr_src[j + 5], s6 = csr_src[j + 6], s7 = csr_src[j + 7];
    float4 v0 = P4[s0 * 4 + c4], v1 = P4[s1 * 4 + c4];
    float4 v2 = P4[s2 * 4 + c4], v3 = P4[s3 * 4 + c4];
    float4 v4 = P4[s4 * 4 + c4], v5 = P4[s5 * 4 + c4];
    float4 v6 = P4[s6 * 4 + c4], v7 = P4[s7 * 4 + c4];
    a0.x += v0.x; a0.y += v0.y; a0.z += v0.z; a0.w += v0.w;
    a1.x += v1.x; a1.y += v1.y; a1.z += v1.z; a1.w += v1.w;
    a0.x += v2.x; a0.y += v2.y; a0.z += v2.z; a0.w += v2.w;
    a1.x += v3.x; a1.y += v3.y; a1.z += v3.z; a1.w += v3.w;
    a0.x += v4.x; a0.y += v4.y; a0.z += v4.z; a0.w += v4.w;
    a1.x += v5.x; a1.y += v5.y; a1.z += v5.z; a1.w += v5.w;
    a0.x += v6.x; a0.y += v6.y; a0.z += v6.z; a0.w += v6.w;
    a1.x += v7.x; a1.y += v7.y; a1.z += v7.z; a1.w += v7.w;
  }
  for (; j + 2 <= re; j += 2) {
    int s0 = csr_src[j], s1 = csr_src[j + 1];
    float4 v0 = P4[s0 * 4 + c4];
    float4 v1 = P4[s1 * 4 + c4];
    a0.x += v0.x; a0.y += v0.y; a0.z += v0.z; a0.w += v0.w;
    a1.x += v1.x; a1.y += v1.y; a1.z += v1.z; a1.w += v1.w;
  }
  if (j < re) {
    int s = csr_src[j];
    float4 v = P4[s * 4 + c4];
    a0.x += v.x; a0.y += v.y; a0.z += v.z; a0.w += v.w;
  }
  const float dn = dis[n];
  const float4 bb = ((const float4*)bias)[chunk * 4 + c4];
  float4 r;
  r.x = (a0.x + a1.x) * dn + bb.x;
  r.y = (a0.y + a1.y) * dn + bb.y;
  r.z = (a0.z + a1.z) * dn + bb.z;
  r.w = (a0.w + a1.w) * dn + bb.w;
  r.x = (r.x >= 0.f) ? r.x : 0.01f * r.x;
  r.y = (r.y >= 0.f) ? r.y : 0.01f * r.y;
  r.z = (r.z >= 0.f) ? r.z : 0.01f * r.z;
  r.w = (r.w >= 0.f) ? r.w : 0.01f * r.w;
  ((float4*)out)[n * (HD / 4) + chunk * 4 + c4] = r;
}

extern "C" void kernel_launch(void* const* d_in, const int* in_sizes, int n_in,
                              void* d_out, int out_size, void* d_ws, size_t ws_size,
                              hipStream_t stream) {
  const float* x  = (const float*)d_in[0];
  const int*   ei = (const int*)d_in[1];
  const float* W0 = (const float*)d_in[2];
  const float* b0 = (const float*)d_in[3];
  const float* W1 = (const float*)d_in[4];
  const float* b1 = (const float*)d_in[5];
  float* out = (float*)d_out;
  const int* src = ei;        // edge_index[0] = message source
  const int* dst = ei + NE;   // edge_index[1] = aggregation target

  char* p = (char*)d_ws;
  int*   deg       = (int*)p;    p += 50048 * 4;
  float* dis       = (float*)p;  p += 50048 * 4;
  int*   row_start = (int*)p;    p += 50052 * 4;
  int*   cursor    = (int*)p;    p += 50048 * 4;
  int*   partial   = (int*)p;    p += 256 * 4;
  int*   perm      = (int*)p;    p += 50048 * 4;
  int*   csr       = (int*)p;    p += 850048 * 4;
  float* bufA      = (float*)p;  // 6.4M floats (25.6 MB) in 8 panels
  // sort scratch aliases bufA (dead until first GEMM)
  int*   hist2     = (int*)bufA;          // 65536
  int*   partial2  = hist2 + NH2;         // 256

  // graph build (once, reused by both layers)
  k_init_deg<<<196, 256, 0, stream>>>(deg);
  k_count<<<3125, 256, 0, stream>>>(dst, deg);
  k_blocksum<<<NB, 256, 0, stream>>>(deg, partial, NN);
  k_scanp<<<1, 256, 0, stream>>>(partial, NB);
  k_scatter<<<NB, 256, 0, stream>>>(deg, partial, row_start, cursor, dis);
  k_fill<<<(EH + 255) / 256, 256, 0, stream>>>(src, dst, cursor, csr);

  // degree counting-sort -> perm (2-level bins, low contention)
  hipMemsetAsync(hist2, 0, NH2 * 4, stream);
  k_hist2<<<196, 256, 0, stream>>>(deg, hist2);
  k_blocksum<<<NH2 / 256, 256, 0, stream>>>(hist2, partial2, NH2);
  k_scanp<<<1, 256, 0, stream>>>(partial2, 256);
  k_excl<<<NH2 / 256, 256, 0, stream>>>(hist2, partial2, NH2);
  k_perm2<<<196, 256, 0, stream>>>(deg, hist2, perm);

  const int AGG_GRID = NCH * ((NN + 63) / 64);   // 8 * 782 = 6256 blocks
  // layer 1
  k_gemm<<<(NN + GR - 1) / GR, 256, 0, stream>>>(x, W0, dis, bufA);
  k_agg<<<AGG_GRID, 256, 0, stream>>>(bufA, dis, row_start, csr, perm, b0, out);
  // layer 2
  k_gemm<<<(NN + GR - 1) / GR, 256, 0, stream>>>(out, W1, dis, bufA);
  k_agg<<<AGG_GRID, 256, 0, stream>>>(bufA, dis, row_start, csr, perm, b1, out);
}

// Round 7
// 343.585 us; speedup vs baseline: 1.9323x; 1.0778x over previous
//
#include <hip/hip_runtime.h>

#define NN 50000
#define NE 800000
#define EH (NE + NN)   // 850000 edges incl. self-loops
#define HD 128
#define NB 196         // ceil(NN/256)
#define NCH 8          // column chunks (one per XCD)
#define CPW 16         // cols per chunk
#define PSTR (NN * CPW)  // floats per panel = 800000
// windowed counting-sort: sort by degree WITHIN each 1024-node window
#define WLOG 10
#define NWIN 49        // ceil(NN/1024)
#define DBIN 64        // degree bins (clamped)
#define DSUB 4         // sub-bins to decontend atomics
#define NH2 (NWIN * DBIN * DSUB)   // 12544 bins
#define NH2B ((NH2 + 255) / 256)   // 49 scan blocks

// ---------------- graph build ----------------
__global__ void k_init_deg(int* __restrict__ deg) {
  int i = blockIdx.x * 256 + threadIdx.x;
  if (i < NN) deg[i] = 1;   // self-loop contributes 1
}

__global__ void k_count(const int* __restrict__ dst, int* __restrict__ deg) {
  int e = blockIdx.x * 256 + threadIdx.x;
  if (e < NE) atomicAdd(&deg[dst[e]], 1);
}

// generic per-block sums (256/block)
__global__ __launch_bounds__(256) void k_blocksum(const int* __restrict__ in,
                                                  int* __restrict__ partial, int nelem) {
  int i = blockIdx.x * 256 + threadIdx.x;
  int v = (i < nelem) ? in[i] : 0;
  #pragma unroll
  for (int off = 32; off >= 1; off >>= 1) v += __shfl_down(v, off);
  __shared__ int ws[4];
  if ((threadIdx.x & 63) == 0) ws[threadIdx.x >> 6] = v;
  __syncthreads();
  if (threadIdx.x == 0) partial[blockIdx.x] = ws[0] + ws[1] + ws[2] + ws[3];
}

// generic small exclusive scan (n <= 256), one block of 256
__global__ __launch_bounds__(256) void k_scanp(int* __restrict__ data, int n) {
  __shared__ int lds[256];
  int t = threadIdx.x;
  int v = (t < n) ? data[t] : 0;
  lds[t] = v;
  __syncthreads();
  #pragma unroll
  for (int off = 1; off < 256; off <<= 1) {
    int u = (t >= off) ? lds[t - off] : 0;
    __syncthreads();
    lds[t] += u;
    __syncthreads();
  }
  if (t < n) data[t] = lds[t] - v;   // exclusive
}

// row_start/cursor + fused dis = rsqrt(deg)
__global__ __launch_bounds__(256) void k_scatter(const int* __restrict__ deg,
                                                 const int* __restrict__ partial,
                                                 int* __restrict__ row_start,
                                                 int* __restrict__ cursor,
                                                 float* __restrict__ dis) {
  __shared__ int lds[256];
  int t = threadIdx.x;
  int i = blockIdx.x * 256 + t;
  int v = (i < NN) ? deg[i] : 0;
  lds[t] = v;
  __syncthreads();
  #pragma unroll
  for (int off = 1; off < 256; off <<= 1) {
    int u = (t >= off) ? lds[t - off] : 0;
    __syncthreads();
    lds[t] += u;
    __syncthreads();
  }
  int ex = lds[t] - v + partial[blockIdx.x];
  if (i < NN) {
    row_start[i] = ex;
    cursor[i] = ex;
    dis[i] = rsqrtf((float)v);   // deg >= 1 always
    if (i == NN - 1) row_start[NN] = ex + v;
  }
}

__global__ void k_fill(const int* __restrict__ src, const int* __restrict__ dst,
                       int* __restrict__ cursor, int* __restrict__ csr_src) {
  int e = blockIdx.x * 256 + threadIdx.x;
  if (e >= EH) return;
  int s, d;
  if (e < NE) { s = src[e]; d = dst[e]; }
  else        { s = e - NE; d = s; }          // self-loop
  int pos = atomicAdd(&cursor[d], 1);
  csr_src[pos] = s;
}

// ------------- windowed degree counting-sort ----------------------------------
// bin = (window, clamp(deg,63), node&3). Windows are 1024 consecutive node ids,
// so perm keeps index locality (csr/out) while making wave degrees uniform.
__device__ __forceinline__ int sort_bin(int i, int d) {
  if (d > DBIN - 1) d = DBIN - 1;
  return (((i >> WLOG) * DBIN + d) * DSUB) + (i & (DSUB - 1));
}

__global__ void k_hist2(const int* __restrict__ deg, int* __restrict__ h) {
  int i = blockIdx.x * 256 + threadIdx.x;
  if (i < NN) atomicAdd(&h[sort_bin(i, deg[i])], 1);
}

// generic in-place exclusive scan apply
__global__ __launch_bounds__(256) void k_excl(int* __restrict__ data,
                                              const int* __restrict__ partial, int nelem) {
  __shared__ int lds[256];
  int t = threadIdx.x;
  int i = blockIdx.x * 256 + t;
  int v = (i < nelem) ? data[i] : 0;
  lds[t] = v;
  __syncthreads();
  #pragma unroll
  for (int off = 1; off < 256; off <<= 1) {
    int u = (t >= off) ? lds[t - off] : 0;
    __syncthreads();
    lds[t] += u;
    __syncthreads();
  }
  if (i < nelem) data[i] = lds[t] - v + partial[blockIdx.x];
}

__global__ void k_perm2(const int* __restrict__ deg, int* __restrict__ h,
                        int* __restrict__ perm) {
  int i = blockIdx.x * 256 + threadIdx.x;
  if (i < NN) {
    int pos = atomicAdd(&h[sort_bin(i, deg[i])], 1);
    perm[pos] = i;
  }
}

// ---------------- dense GEMM: C = dis[row] * (A[NN,128] @ W[128,128]) -------------
// Output in chunk-panel layout: panel p holds cols [16p,16p+16), contiguous 3.2 MB.
#define GR 128
__global__ __launch_bounds__(256, 1) void k_gemm(const float* __restrict__ A,
                                                 const float* __restrict__ W,
                                                 const float* __restrict__ dis,
                                                 float* __restrict__ C) {
  __shared__ float As[GR][HD + 4];
  __shared__ float Ws[HD * HD];
  const int tid = threadIdx.x;
  const int r0 = blockIdx.x * GR;
  #pragma unroll
  for (int m = 0; m < 16; ++m) {
    int f = tid + m * 256;
    ((float4*)Ws)[f] = ((const float4*)W)[f];
  }
  #pragma unroll
  for (int m = 0; m < 16; ++m) {
    int f = tid + m * 256;
    int r = f >> 5, c4 = f & 31;
    int gr_ = r0 + r;
    float4 v = make_float4(0.f, 0.f, 0.f, 0.f);
    if (gr_ < NN) v = ((const float4*)A)[gr_ * 32 + c4];
    *(float4*)&As[r][c4 * 4] = v;
  }
  __syncthreads();
  const int tg = tid >> 4;
  const int tc = tid & 15;
  const int cc = tc * 4;
  float acc[8][8];
  #pragma unroll
  for (int j = 0; j < 8; ++j)
    #pragma unroll
    for (int c = 0; c < 8; ++c) acc[j][c] = 0.f;

  for (int k = 0; k < HD; k += 4) {
    float4 a[8];
    #pragma unroll
    for (int j = 0; j < 8; ++j) a[j] = *(const float4*)&As[tg + 16 * j][k];
    #pragma unroll
    for (int kk = 0; kk < 4; ++kk) {
      float4 w0 = *(const float4*)&Ws[(k + kk) * HD + cc];
      float4 w1 = *(const float4*)&Ws[(k + kk) * HD + cc + 64];
      #pragma unroll
      for (int j = 0; j < 8; ++j) {
        float av = (kk == 0) ? a[j].x : (kk == 1) ? a[j].y : (kk == 2) ? a[j].z : a[j].w;
        acc[j][0] += av * w0.x; acc[j][1] += av * w0.y;
        acc[j][2] += av * w0.z; acc[j][3] += av * w0.w;
        acc[j][4] += av * w1.x; acc[j][5] += av * w1.y;
        acc[j][6] += av * w1.z; acc[j][7] += av * w1.w;
      }
    }
  }
  const int p0 = cc >> 4;
  const int pc = cc & 15;
  #pragma unroll
  for (int j = 0; j < 8; ++j) {
    int row = r0 + tg + 16 * j;
    if (row < NN) {
      const float dsc = dis[row];
      *(float4*)&C[p0 * PSTR + row * CPW + pc] =
          make_float4(acc[j][0] * dsc, acc[j][1] * dsc, acc[j][2] * dsc, acc[j][3] * dsc);
      *(float4*)&C[(p0 + 4) * PSTR + row * CPW + pc] =
          make_float4(acc[j][4] * dsc, acc[j][5] * dsc, acc[j][6] * dsc, acc[j][7] * dsc);
    }
  }
}

// ---------------- CSR gather-aggregate (window-sorted, float4, 8-deep MLP) --------
// thread = (node, 4 cols). Wave = 16 degree-adjacent nodes from ONE 1024-node
// window -> uniform trips AND index-local csr/out. chunk = bid&7 -> XCD panel.
__global__ __launch_bounds__(256) void k_agg(const float* __restrict__ Tpanels,
                                             const float* __restrict__ dis,
                                             const int* __restrict__ row_start,
                                             const int* __restrict__ csr_src,
                                             const int* __restrict__ perm,
                                             const float* __restrict__ bias,
                                             float* __restrict__ out) {
  const int tid = threadIdx.x;
  const int chunk = blockIdx.x & (NCH - 1);
  const int idx = (blockIdx.x >> 3) * 64 + (tid >> 2);
  if (idx >= NN) return;
  const int n = perm[idx];
  const int c4 = tid & 3;
  const float4* __restrict__ P4 = (const float4*)(Tpanels + chunk * PSTR);

  const int rs = row_start[n], re = row_start[n + 1];
  float4 a0 = make_float4(0.f, 0.f, 0.f, 0.f);
  float4 a1 = make_float4(0.f, 0.f, 0.f, 0.f);
  int j = rs;
  for (; j + 8 <= re; j += 8) {
    int s0 = csr_src[j],     s1 = csr_src[j + 1], s2 = csr_src[j + 2], s3 = csr_src[j + 3];
    int s4 = csr_src[j + 4], s5 = csr_src[j + 5], s6 = csr_src[j + 6], s7 = csr_src[j + 7];
    float4 v0 = P4[s0 * 4 + c4], v1 = P4[s1 * 4 + c4];
    float4 v2 = P4[s2 * 4 + c4], v3 = P4[s3 * 4 + c4];
    float4 v4 = P4[s4 * 4 + c4], v5 = P4[s5 * 4 + c4];
    float4 v6 = P4[s6 * 4 + c4], v7 = P4[s7 * 4 + c4];
    a0.x += v0.x; a0.y += v0.y; a0.z += v0.z; a0.w += v0.w;
    a1.x += v1.x; a1.y += v1.y; a1.z += v1.z; a1.w += v1.w;
    a0.x += v2.x; a0.y += v2.y; a0.z += v2.z; a0.w += v2.w;
    a1.x += v3.x; a1.y += v3.y; a1.z += v3.z; a1.w += v3.w;
    a0.x += v4.x; a0.y += v4.y; a0.z += v4.z; a0.w += v4.w;
    a1.x += v5.x; a1.y += v5.y; a1.z += v5.z; a1.w += v5.w;
    a0.x += v6.x; a0.y += v6.y; a0.z += v6.z; a0.w += v6.w;
    a1.x += v7.x; a1.y += v7.y; a1.z += v7.z; a1.w += v7.w;
  }
  for (; j + 2 <= re; j += 2) {
    int s0 = csr_src[j], s1 = csr_src[j + 1];
    float4 v0 = P4[s0 * 4 + c4];
    float4 v1 = P4[s1 * 4 + c4];
    a0.x += v0.x; a0.y += v0.y; a0.z += v0.z; a0.w += v0.w;
    a1.x += v1.x; a1.y += v1.y; a1.z += v1.z; a1.w += v1.w;
  }
  if (j < re) {
    int s = csr_src[j];
    float4 v = P4[s * 4 + c4];
    a0.x += v.x; a0.y += v.y; a0.z += v.z; a0.w += v.w;
  }
  const float dn = dis[n];
  const float4 bb = ((const float4*)bias)[chunk * 4 + c4];
  float4 r;
  r.x = (a0.x + a1.x) * dn + bb.x;
  r.y = (a0.y + a1.y) * dn + bb.y;
  r.z = (a0.z + a1.z) * dn + bb.z;
  r.w = (a0.w + a1.w) * dn + bb.w;
  r.x = (r.x >= 0.f) ? r.x : 0.01f * r.x;
  r.y = (r.y >= 0.f) ? r.y : 0.01f * r.y;
  r.z = (r.z >= 0.f) ? r.z : 0.01f * r.z;
  r.w = (r.w >= 0.f) ? r.w : 0.01f * r.w;
  ((float4*)out)[n * (HD / 4) + chunk * 4 + c4] = r;
}

extern "C" void kernel_launch(void* const* d_in, const int* in_sizes, int n_in,
                              void* d_out, int out_size, void* d_ws, size_t ws_size,
                              hipStream_t stream) {
  const float* x  = (const float*)d_in[0];
  const int*   ei = (const int*)d_in[1];
  const float* W0 = (const float*)d_in[2];
  const float* b0 = (const float*)d_in[3];
  const float* W1 = (const float*)d_in[4];
  const float* b1 = (const float*)d_in[5];
  float* out = (float*)d_out;
  const int* src = ei;        // edge_index[0] = message source
  const int* dst = ei + NE;   // edge_index[1] = aggregation target

  char* p = (char*)d_ws;
  int*   deg       = (int*)p;    p += 50048 * 4;
  float* dis       = (float*)p;  p += 50048 * 4;
  int*   row_start = (int*)p;    p += 50052 * 4;
  int*   cursor    = (int*)p;    p += 50048 * 4;
  int*   partial   = (int*)p;    p += 256 * 4;
  int*   perm      = (int*)p;    p += 50048 * 4;
  int*   csr       = (int*)p;    p += 850048 * 4;
  float* bufA      = (float*)p;  // 6.4M floats (25.6 MB) in 8 panels
  // sort scratch aliases bufA (dead until first GEMM)
  int*   hist2     = (int*)bufA;          // 12544
  int*   partial2  = hist2 + NH2;         // 49

  // graph build (once, reused by both layers)
  k_init_deg<<<196, 256, 0, stream>>>(deg);
  k_count<<<3125, 256, 0, stream>>>(dst, deg);
  k_blocksum<<<NB, 256, 0, stream>>>(deg, partial, NN);
  k_scanp<<<1, 256, 0, stream>>>(partial, NB);
  k_scatter<<<NB, 256, 0, stream>>>(deg, partial, row_start, cursor, dis);
  k_fill<<<(EH + 255) / 256, 256, 0, stream>>>(src, dst, cursor, csr);

  // windowed degree counting-sort -> perm
  hipMemsetAsync(hist2, 0, NH2 * 4, stream);
  k_hist2<<<196, 256, 0, stream>>>(deg, hist2);
  k_blocksum<<<NH2B, 256, 0, stream>>>(hist2, partial2, NH2);
  k_scanp<<<1, 256, 0, stream>>>(partial2, NH2B);
  k_excl<<<NH2B, 256, 0, stream>>>(hist2, partial2, NH2);
  k_perm2<<<196, 256, 0, stream>>>(deg, hist2, perm);

  const int AGG_GRID = NCH * ((NN + 63) / 64);   // 8 * 782 = 6256 blocks
  // layer 1
  k_gemm<<<(NN + GR - 1) / GR, 256, 0, stream>>>(x, W0, dis, bufA);
  k_agg<<<AGG_GRID, 256, 0, stream>>>(bufA, dis, row_start, csr, perm, b0, out);
  // layer 2
  k_gemm<<<(NN + GR - 1) / GR, 256, 0, stream>>>(out, W1, dis, bufA);
  k_agg<<<AGG_GRID, 256, 0, stream>>>(bufA, dis, row_start, csr, perm, b1, out);
}

// Round 8
// 340.678 us; speedup vs baseline: 1.9488x; 1.0085x over previous
//
#include <hip/hip_runtime.h>

#define NN 50000
#define NE 800000
#define EH (NE + NN)   // 850000 edges incl. self-loops
#define HD 128
#define NB 196         // ceil(NN/256)
#define NCH 8          // column chunks (one per XCD)
#define CPW 16         // cols per chunk
#define PSTR ((NN + 1) * CPW)  // floats per panel = 800016 (row NN = dummy zeros)
// windowed counting-sort: sort by degree WITHIN each 1024-node window
#define WLOG 10
#define NWIN 49        // ceil(NN/1024)
#define DBIN 64        // degree bins (clamped)
#define DSUB 4         // sub-bins to decontend atomics
#define NH2 (NWIN * DBIN * DSUB)   // 12544 bins
#define NH2B ((NH2 + 255) / 256)   // 49 scan blocks

// ---------------- graph build ----------------
__global__ void k_init_deg(int* __restrict__ deg) {
  int i = blockIdx.x * 256 + threadIdx.x;
  if (i < NN) deg[i] = 1;   // self-loop contributes 1
}

__global__ void k_count(const int* __restrict__ dst, int* __restrict__ deg) {
  int e = blockIdx.x * 256 + threadIdx.x;
  if (e < NE) atomicAdd(&deg[dst[e]], 1);
}

// per-block sums of PADDED degree ((d+3)&~3)
__global__ __launch_bounds__(256) void k_blocksum_pad(const int* __restrict__ deg,
                                                      int* __restrict__ partial) {
  int i = blockIdx.x * 256 + threadIdx.x;
  int v = (i < NN) ? ((deg[i] + 3) & ~3) : 0;
  #pragma unroll
  for (int off = 32; off >= 1; off >>= 1) v += __shfl_down(v, off);
  __shared__ int ws[4];
  if ((threadIdx.x & 63) == 0) ws[threadIdx.x >> 6] = v;
  __syncthreads();
  if (threadIdx.x == 0) partial[blockIdx.x] = ws[0] + ws[1] + ws[2] + ws[3];
}

// generic per-block sums
__global__ __launch_bounds__(256) void k_blocksum(const int* __restrict__ in,
                                                  int* __restrict__ partial, int nelem) {
  int i = blockIdx.x * 256 + threadIdx.x;
  int v = (i < nelem) ? in[i] : 0;
  #pragma unroll
  for (int off = 32; off >= 1; off >>= 1) v += __shfl_down(v, off);
  __shared__ int ws[4];
  if ((threadIdx.x & 63) == 0) ws[threadIdx.x >> 6] = v;
  __syncthreads();
  if (threadIdx.x == 0) partial[blockIdx.x] = ws[0] + ws[1] + ws[2] + ws[3];
}

// generic small exclusive scan (n <= 256), one block of 256
__global__ __launch_bounds__(256) void k_scanp(int* __restrict__ data, int n) {
  __shared__ int lds[256];
  int t = threadIdx.x;
  int v = (t < n) ? data[t] : 0;
  lds[t] = v;
  __syncthreads();
  #pragma unroll
  for (int off = 1; off < 256; off <<= 1) {
    int u = (t >= off) ? lds[t - off] : 0;
    __syncthreads();
    lds[t] += u;
    __syncthreads();
  }
  if (t < n) data[t] = lds[t] - v;   // exclusive
}

// row_start (padded, 4-aligned) / cursor + fused dis = rsqrt(real deg)
__global__ __launch_bounds__(256) void k_scatter(const int* __restrict__ deg,
                                                 const int* __restrict__ partial,
                                                 int* __restrict__ row_start,
                                                 int* __restrict__ cursor,
                                                 float* __restrict__ dis) {
  __shared__ int lds[256];
  int t = threadIdx.x;
  int i = blockIdx.x * 256 + t;
  int vr = (i < NN) ? deg[i] : 0;
  int v = (vr + 3) & ~3;
  lds[t] = v;
  __syncthreads();
  #pragma unroll
  for (int off = 1; off < 256; off <<= 1) {
    int u = (t >= off) ? lds[t - off] : 0;
    __syncthreads();
    lds[t] += u;
    __syncthreads();
  }
  int ex = lds[t] - v + partial[blockIdx.x];
  if (i < NN) {
    row_start[i] = ex;
    cursor[i] = ex;
    dis[i] = rsqrtf((float)vr);   // deg >= 1 always
    if (i == NN - 1) row_start[NN] = ex + v;
  }
}

__global__ void k_fill(const int* __restrict__ src, const int* __restrict__ dst,
                       int* __restrict__ cursor, int* __restrict__ csr_src) {
  int e = blockIdx.x * 256 + threadIdx.x;
  if (e >= EH) return;
  int s, d;
  if (e < NE) { s = src[e]; d = dst[e]; }
  else        { s = e - NE; d = s; }          // self-loop
  int pos = atomicAdd(&cursor[d], 1);
  csr_src[pos] = s;
}

// fill each node's padding slots (up to 3) with dummy row index NN
__global__ void k_pad(const int* __restrict__ deg, const int* __restrict__ row_start,
                      int* __restrict__ csr_src) {
  int n = blockIdx.x * 256 + threadIdx.x;
  if (n < NN) {
    int d = deg[n];
    int s = row_start[n] + d;
    int e = row_start[n] + ((d + 3) & ~3);
    for (int q = s; q < e; ++q) csr_src[q] = NN;
  }
}

// ------------- windowed degree counting-sort ----------------------------------
__device__ __forceinline__ int sort_bin(int i, int d) {
  if (d > DBIN - 1) d = DBIN - 1;
  return (((i >> WLOG) * DBIN + d) * DSUB) + (i & (DSUB - 1));
}

// also zeroes the 8 panels' dummy rows (runs before any GEMM writes panels)
__global__ void k_hist2(const int* __restrict__ deg, int* __restrict__ h,
                        float* __restrict__ panels) {
  int i = blockIdx.x * 256 + threadIdx.x;
  if (i < NCH * CPW) {   // 128 threads zero 8 x 16 dummy floats
    int pl = i >> 4;
    panels[(size_t)pl * PSTR + NN * CPW + (i & 15)] = 0.f;
  }
  if (i < NN) atomicAdd(&h[sort_bin(i, deg[i])], 1);
}

__global__ __launch_bounds__(256) void k_excl(int* __restrict__ data,
                                              const int* __restrict__ partial, int nelem) {
  __shared__ int lds[256];
  int t = threadIdx.x;
  int i = blockIdx.x * 256 + t;
  int v = (i < nelem) ? data[i] : 0;
  lds[t] = v;
  __syncthreads();
  #pragma unroll
  for (int off = 1; off < 256; off <<= 1) {
    int u = (t >= off) ? lds[t - off] : 0;
    __syncthreads();
    lds[t] += u;
    __syncthreads();
  }
  if (i < nelem) data[i] = lds[t] - v + partial[blockIdx.x];
}

__global__ void k_perm2(const int* __restrict__ deg, int* __restrict__ h,
                        int* __restrict__ perm) {
  int i = blockIdx.x * 256 + threadIdx.x;
  if (i < NN) {
    int pos = atomicAdd(&h[sort_bin(i, deg[i])], 1);
    perm[pos] = i;
  }
}

// ---------------- dense GEMM: C = dis[row] * (A[NN,128] @ W[128,128]) -------------
// Output in chunk-panel layout: panel p holds cols [16p,16p+16), stride PSTR.
#define GR 128
__global__ __launch_bounds__(256, 1) void k_gemm(const float* __restrict__ A,
                                                 const float* __restrict__ W,
                                                 const float* __restrict__ dis,
                                                 float* __restrict__ C) {
  __shared__ float As[GR][HD + 4];
  __shared__ float Ws[HD * HD];
  const int tid = threadIdx.x;
  const int r0 = blockIdx.x * GR;
  #pragma unroll
  for (int m = 0; m < 16; ++m) {
    int f = tid + m * 256;
    ((float4*)Ws)[f] = ((const float4*)W)[f];
  }
  #pragma unroll
  for (int m = 0; m < 16; ++m) {
    int f = tid + m * 256;
    int r = f >> 5, c4 = f & 31;
    int gr_ = r0 + r;
    float4 v = make_float4(0.f, 0.f, 0.f, 0.f);
    if (gr_ < NN) v = ((const float4*)A)[gr_ * 32 + c4];
    *(float4*)&As[r][c4 * 4] = v;
  }
  __syncthreads();
  const int tg = tid >> 4;
  const int tc = tid & 15;
  const int cc = tc * 4;
  float acc[8][8];
  #pragma unroll
  for (int j = 0; j < 8; ++j)
    #pragma unroll
    for (int c = 0; c < 8; ++c) acc[j][c] = 0.f;

  for (int k = 0; k < HD; k += 4) {
    float4 a[8];
    #pragma unroll
    for (int j = 0; j < 8; ++j) a[j] = *(const float4*)&As[tg + 16 * j][k];
    #pragma unroll
    for (int kk = 0; kk < 4; ++kk) {
      float4 w0 = *(const float4*)&Ws[(k + kk) * HD + cc];
      float4 w1 = *(const float4*)&Ws[(k + kk) * HD + cc + 64];
      #pragma unroll
      for (int j = 0; j < 8; ++j) {
        float av = (kk == 0) ? a[j].x : (kk == 1) ? a[j].y : (kk == 2) ? a[j].z : a[j].w;
        acc[j][0] += av * w0.x; acc[j][1] += av * w0.y;
        acc[j][2] += av * w0.z; acc[j][3] += av * w0.w;
        acc[j][4] += av * w1.x; acc[j][5] += av * w1.y;
        acc[j][6] += av * w1.z; acc[j][7] += av * w1.w;
      }
    }
  }
  const int p0 = cc >> 4;
  const int pc = cc & 15;
  #pragma unroll
  for (int j = 0; j < 8; ++j) {
    int row = r0 + tg + 16 * j;
    if (row < NN) {
      const float dsc = dis[row];
      *(float4*)&C[(size_t)p0 * PSTR + row * CPW + pc] =
          make_float4(acc[j][0] * dsc, acc[j][1] * dsc, acc[j][2] * dsc, acc[j][3] * dsc);
      *(float4*)&C[(size_t)(p0 + 4) * PSTR + row * CPW + pc] =
          make_float4(acc[j][4] * dsc, acc[j][5] * dsc, acc[j][6] * dsc, acc[j][7] * dsc);
    }
  }
}

// ---------------- CSR gather-aggregate (window-sorted, int4 csr, no tail) ---------
// thread = (node, 4 cols). Wave = 16 degree-adjacent nodes from ONE 1024-node
// window. Segments are 4-padded with dummy row NN (zeros) -> batches of 4 edges:
// one int4 csr load (broadcast across the node's 4 lanes) + 4 float4 gathers.
__global__ __launch_bounds__(256) void k_agg(const float* __restrict__ Tpanels,
                                             const float* __restrict__ dis,
                                             const int* __restrict__ row_start,
                                             const int* __restrict__ csr_src,
                                             const int* __restrict__ perm,
                                             const float* __restrict__ bias,
                                             float* __restrict__ out) {
  const int tid = threadIdx.x;
  const int chunk = blockIdx.x & (NCH - 1);
  const int idx = (blockIdx.x >> 3) * 64 + (tid >> 2);
  if (idx >= NN) return;
  const int n = perm[idx];
  const int c4 = tid & 3;
  const float4* __restrict__ P4 = (const float4*)(Tpanels + (size_t)chunk * PSTR);
  const int4* __restrict__ csr4 = (const int4*)csr_src;

  const int jb = row_start[n] >> 2, je = row_start[n + 1] >> 2;   // 4-aligned
  float4 a0 = make_float4(0.f, 0.f, 0.f, 0.f);
  float4 a1 = make_float4(0.f, 0.f, 0.f, 0.f);
  int j = jb;
  for (; j + 2 <= je; j += 2) {
    int4 sA = csr4[j], sB = csr4[j + 1];
    float4 v0 = P4[sA.x * 4 + c4], v1 = P4[sA.y * 4 + c4];
    float4 v2 = P4[sA.z * 4 + c4], v3 = P4[sA.w * 4 + c4];
    float4 v4 = P4[sB.x * 4 + c4], v5 = P4[sB.y * 4 + c4];
    float4 v6 = P4[sB.z * 4 + c4], v7 = P4[sB.w * 4 + c4];
    a0.x += v0.x; a0.y += v0.y; a0.z += v0.z; a0.w += v0.w;
    a1.x += v1.x; a1.y += v1.y; a1.z += v1.z; a1.w += v1.w;
    a0.x += v2.x; a0.y += v2.y; a0.z += v2.z; a0.w += v2.w;
    a1.x += v3.x; a1.y += v3.y; a1.z += v3.z; a1.w += v3.w;
    a0.x += v4.x; a0.y += v4.y; a0.z += v4.z; a0.w += v4.w;
    a1.x += v5.x; a1.y += v5.y; a1.z += v5.z; a1.w += v5.w;
    a0.x += v6.x; a0.y += v6.y; a0.z += v6.z; a0.w += v6.w;
    a1.x += v7.x; a1.y += v7.y; a1.z += v7.z; a1.w += v7.w;
  }
  if (j < je) {
    int4 sA = csr4[j];
    float4 v0 = P4[sA.x * 4 + c4], v1 = P4[sA.y * 4 + c4];
    float4 v2 = P4[sA.z * 4 + c4], v3 = P4[sA.w * 4 + c4];
    a0.x += v0.x; a0.y += v0.y; a0.z += v0.z; a0.w += v0.w;
    a1.x += v1.x; a1.y += v1.y; a1.z += v1.z; a1.w += v1.w;
    a0.x += v2.x; a0.y += v2.y; a0.z += v2.z; a0.w += v2.w;
    a1.x += v3.x; a1.y += v3.y; a1.z += v3.z; a1.w += v3.w;
  }
  const float dn = dis[n];
  const float4 bb = ((const float4*)bias)[chunk * 4 + c4];
  float4 r;
  r.x = (a0.x + a1.x) * dn + bb.x;
  r.y = (a0.y + a1.y) * dn + bb.y;
  r.z = (a0.z + a1.z) * dn + bb.z;
  r.w = (a0.w + a1.w) * dn + bb.w;
  r.x = (r.x >= 0.f) ? r.x : 0.01f * r.x;
  r.y = (r.y >= 0.f) ? r.y : 0.01f * r.y;
  r.z = (r.z >= 0.f) ? r.z : 0.01f * r.z;
  r.w = (r.w >= 0.f) ? r.w : 0.01f * r.w;
  ((float4*)out)[(size_t)n * (HD / 4) + chunk * 4 + c4] = r;
}

extern "C" void kernel_launch(void* const* d_in, const int* in_sizes, int n_in,
                              void* d_out, int out_size, void* d_ws, size_t ws_size,
                              hipStream_t stream) {
  const float* x  = (const float*)d_in[0];
  const int*   ei = (const int*)d_in[1];
  const float* W0 = (const float*)d_in[2];
  const float* b0 = (const float*)d_in[3];
  const float* W1 = (const float*)d_in[4];
  const float* b1 = (const float*)d_in[5];
  float* out = (float*)d_out;
  const int* src = ei;        // edge_index[0] = message source
  const int* dst = ei + NE;   // edge_index[1] = aggregation target

  char* p = (char*)d_ws;
  int*   deg       = (int*)p;    p += 50048 * 4;
  float* dis       = (float*)p;  p += 50048 * 4;
  int*   row_start = (int*)p;    p += 50052 * 4;
  int*   cursor    = (int*)p;    p += 50048 * 4;
  int*   partial   = (int*)p;    p += 256 * 4;
  int*   perm      = (int*)p;    p += 50048 * 4;
  int*   csr       = (int*)p;    p += 1000064 * 4;   // padded: <= 850000 + 3*50000
  float* bufA      = (float*)p;  // 8 panels x 800016 floats (~25.6 MB)
  // sort scratch aliases bufA head (dead until first GEMM; dummy rows are at tail)
  int*   hist2     = (int*)bufA;          // 12544
  int*   partial2  = hist2 + NH2;         // 49

  // graph build (once, reused by both layers)
  k_init_deg<<<196, 256, 0, stream>>>(deg);
  k_count<<<3125, 256, 0, stream>>>(dst, deg);
  k_blocksum_pad<<<NB, 256, 0, stream>>>(deg, partial);
  k_scanp<<<1, 256, 0, stream>>>(partial, NB);
  k_scatter<<<NB, 256, 0, stream>>>(deg, partial, row_start, cursor, dis);
  k_fill<<<(EH + 255) / 256, 256, 0, stream>>>(src, dst, cursor, csr);
  k_pad<<<NB, 256, 0, stream>>>(deg, row_start, csr);

  // windowed degree counting-sort -> perm (+ dummy-row zeroing in k_hist2)
  hipMemsetAsync(hist2, 0, NH2 * 4, stream);
  k_hist2<<<196, 256, 0, stream>>>(deg, hist2, bufA);
  k_blocksum<<<NH2B, 256, 0, stream>>>(hist2, partial2, NH2);
  k_scanp<<<1, 256, 0, stream>>>(partial2, NH2B);
  k_excl<<<NH2B, 256, 0, stream>>>(hist2, partial2, NH2);
  k_perm2<<<196, 256, 0, stream>>>(deg, hist2, perm);

  const int AGG_GRID = NCH * ((NN + 63) / 64);   // 8 * 782 = 6256 blocks
  // layer 1
  k_gemm<<<(NN + GR - 1) / GR, 256, 0, stream>>>(x, W0, dis, bufA);
  k_agg<<<AGG_GRID, 256, 0, stream>>>(bufA, dis, row_start, csr, perm, b0, out);
  // layer 2
  k_gemm<<<(NN + GR - 1) / GR, 256, 0, stream>>>(out, W1, dis, bufA);
  k_agg<<<AGG_GRID, 256, 0, stream>>>(bufA, dis, row_start, csr, perm, b1, out);
}

// Round 9
// 292.105 us; speedup vs baseline: 2.2729x; 1.1663x over previous
//
#include <hip/hip_runtime.h>

#define NN 50000
#define NE 800000
#define EH (NE + NN)   // 850000 edges incl. self-loops
#define HD 128
#define NB 196         // ceil(NN/256)
#define NCH 4          // column chunks (each pinned to 2 XCDs)
#define CPW 32         // cols per chunk (bf16 row = 64 B = one cache line)
#define PSTRH ((NN + 1) * CPW)  // halves per panel = 1600032 (row NN = dummy zeros)
// windowed counting-sort: sort by degree WITHIN each 1024-node window
#define WLOG 10
#define NWIN 49
#define DBIN 64
#define DSUB 4
#define NH2 (NWIN * DBIN * DSUB)   // 12544 bins
#define NH2B ((NH2 + 255) / 256)   // 49 scan blocks

__device__ __forceinline__ unsigned short f2bf(float f) {
  union { float f; unsigned int u; } v; v.f = f;
  unsigned int r = v.u + 0x7FFFu + ((v.u >> 16) & 1u);   // RNE
  return (unsigned short)(r >> 16);
}

// ---------------- graph build ----------------
__global__ void k_init_deg(int* __restrict__ deg) {
  int i = blockIdx.x * 256 + threadIdx.x;
  if (i < NN) deg[i] = 1;   // self-loop contributes 1
}

__global__ void k_count(const int* __restrict__ dst, int* __restrict__ deg) {
  int e = blockIdx.x * 256 + threadIdx.x;
  if (e < NE) atomicAdd(&deg[dst[e]], 1);
}

// per-block sums of PADDED degree ((d+3)&~3)
__global__ __launch_bounds__(256) void k_blocksum_pad(const int* __restrict__ deg,
                                                      int* __restrict__ partial) {
  int i = blockIdx.x * 256 + threadIdx.x;
  int v = (i < NN) ? ((deg[i] + 3) & ~3) : 0;
  #pragma unroll
  for (int off = 32; off >= 1; off >>= 1) v += __shfl_down(v, off);
  __shared__ int ws[4];
  if ((threadIdx.x & 63) == 0) ws[threadIdx.x >> 6] = v;
  __syncthreads();
  if (threadIdx.x == 0) partial[blockIdx.x] = ws[0] + ws[1] + ws[2] + ws[3];
}

__global__ __launch_bounds__(256) void k_blocksum(const int* __restrict__ in,
                                                  int* __restrict__ partial, int nelem) {
  int i = blockIdx.x * 256 + threadIdx.x;
  int v = (i < nelem) ? in[i] : 0;
  #pragma unroll
  for (int off = 32; off >= 1; off >>= 1) v += __shfl_down(v, off);
  __shared__ int ws[4];
  if ((threadIdx.x & 63) == 0) ws[threadIdx.x >> 6] = v;
  __syncthreads();
  if (threadIdx.x == 0) partial[blockIdx.x] = ws[0] + ws[1] + ws[2] + ws[3];
}

__global__ __launch_bounds__(256) void k_scanp(int* __restrict__ data, int n) {
  __shared__ int lds[256];
  int t = threadIdx.x;
  int v = (t < n) ? data[t] : 0;
  lds[t] = v;
  __syncthreads();
  #pragma unroll
  for (int off = 1; off < 256; off <<= 1) {
    int u = (t >= off) ? lds[t - off] : 0;
    __syncthreads();
    lds[t] += u;
    __syncthreads();
  }
  if (t < n) data[t] = lds[t] - v;   // exclusive
}

// row_start (padded, 4-aligned) / cursor + fused dis = rsqrt(real deg)
__global__ __launch_bounds__(256) void k_scatter(const int* __restrict__ deg,
                                                 const int* __restrict__ partial,
                                                 int* __restrict__ row_start,
                                                 int* __restrict__ cursor,
                                                 float* __restrict__ dis) {
  __shared__ int lds[256];
  int t = threadIdx.x;
  int i = blockIdx.x * 256 + t;
  int vr = (i < NN) ? deg[i] : 0;
  int v = (vr + 3) & ~3;
  lds[t] = v;
  __syncthreads();
  #pragma unroll
  for (int off = 1; off < 256; off <<= 1) {
    int u = (t >= off) ? lds[t - off] : 0;
    __syncthreads();
    lds[t] += u;
    __syncthreads();
  }
  int ex = lds[t] - v + partial[blockIdx.x];
  if (i < NN) {
    row_start[i] = ex;
    cursor[i] = ex;
    dis[i] = rsqrtf((float)vr);   // deg >= 1 always
    if (i == NN - 1) row_start[NN] = ex + v;
  }
}

__global__ void k_fill(const int* __restrict__ src, const int* __restrict__ dst,
                       int* __restrict__ cursor, int* __restrict__ csr_src) {
  int e = blockIdx.x * 256 + threadIdx.x;
  if (e >= EH) return;
  int s, d;
  if (e < NE) { s = src[e]; d = dst[e]; }
  else        { s = e - NE; d = s; }          // self-loop
  int pos = atomicAdd(&cursor[d], 1);
  csr_src[pos] = s;
}

// fill padding slots (up to 3 per node) with dummy row index NN
__global__ void k_pad(const int* __restrict__ deg, const int* __restrict__ row_start,
                      int* __restrict__ csr_src) {
  int n = blockIdx.x * 256 + threadIdx.x;
  if (n < NN) {
    int d = deg[n];
    int s = row_start[n] + d;
    int e = row_start[n] + ((d + 3) & ~3);
    for (int q = s; q < e; ++q) csr_src[q] = NN;
  }
}

// ------------- windowed degree counting-sort ----------------------------------
__device__ __forceinline__ int sort_bin(int i, int d) {
  if (d > DBIN - 1) d = DBIN - 1;
  return (((i >> WLOG) * DBIN + d) * DSUB) + (i & (DSUB - 1));
}

// also zeroes the panels' dummy rows (runs before any GEMM writes panels)
__global__ void k_hist2(const int* __restrict__ deg, int* __restrict__ h,
                        unsigned short* __restrict__ panels) {
  int i = blockIdx.x * 256 + threadIdx.x;
  if (i < NCH * CPW) {   // 128 threads zero 4 x 32 dummy halves
    int pl = i >> 5;
    panels[(size_t)pl * PSTRH + (size_t)NN * CPW + (i & 31)] = 0;
  }
  if (i < NN) atomicAdd(&h[sort_bin(i, deg[i])], 1);
}

__global__ __launch_bounds__(256) void k_excl(int* __restrict__ data,
                                              const int* __restrict__ partial, int nelem) {
  __shared__ int lds[256];
  int t = threadIdx.x;
  int i = blockIdx.x * 256 + t;
  int v = (i < nelem) ? data[i] : 0;
  lds[t] = v;
  __syncthreads();
  #pragma unroll
  for (int off = 1; off < 256; off <<= 1) {
    int u = (t >= off) ? lds[t - off] : 0;
    __syncthreads();
    lds[t] += u;
    __syncthreads();
  }
  if (i < nelem) data[i] = lds[t] - v + partial[blockIdx.x];
}

__global__ void k_perm2(const int* __restrict__ deg, int* __restrict__ h,
                        int* __restrict__ perm) {
  int i = blockIdx.x * 256 + threadIdx.x;
  if (i < NN) {
    int pos = atomicAdd(&h[sort_bin(i, deg[i])], 1);
    perm[pos] = i;
  }
}

// ------- dense GEMM: Cpanels(bf16) = dis[row] * (A[NN,128] @ W[128,128]) ----------
// panel p (0..3) holds cols [32p, 32p+32) of all rows, bf16, one 64 B line per row.
#define GR 128
__global__ __launch_bounds__(256, 1) void k_gemm(const float* __restrict__ A,
                                                 const float* __restrict__ W,
                                                 const float* __restrict__ dis,
                                                 unsigned short* __restrict__ C) {
  __shared__ float As[GR][HD + 4];
  __shared__ float Ws[HD * HD];
  const int tid = threadIdx.x;
  const int r0 = blockIdx.x * GR;
  #pragma unroll
  for (int m = 0; m < 16; ++m) {
    int f = tid + m * 256;
    ((float4*)Ws)[f] = ((const float4*)W)[f];
  }
  #pragma unroll
  for (int m = 0; m < 16; ++m) {
    int f = tid + m * 256;
    int r = f >> 5, c4 = f & 31;
    int gr_ = r0 + r;
    float4 v = make_float4(0.f, 0.f, 0.f, 0.f);
    if (gr_ < NN) v = ((const float4*)A)[gr_ * 32 + c4];
    *(float4*)&As[r][c4 * 4] = v;
  }
  __syncthreads();
  const int tg = tid >> 4;
  const int tc = tid & 15;
  const int cc = tc * 4;
  float acc[8][8];
  #pragma unroll
  for (int j = 0; j < 8; ++j)
    #pragma unroll
    for (int c = 0; c < 8; ++c) acc[j][c] = 0.f;

  for (int k = 0; k < HD; k += 4) {
    float4 a[8];
    #pragma unroll
    for (int j = 0; j < 8; ++j) a[j] = *(const float4*)&As[tg + 16 * j][k];
    #pragma unroll
    for (int kk = 0; kk < 4; ++kk) {
      float4 w0 = *(const float4*)&Ws[(k + kk) * HD + cc];
      float4 w1 = *(const float4*)&Ws[(k + kk) * HD + cc + 64];
      #pragma unroll
      for (int j = 0; j < 8; ++j) {
        float av = (kk == 0) ? a[j].x : (kk == 1) ? a[j].y : (kk == 2) ? a[j].z : a[j].w;
        acc[j][0] += av * w0.x; acc[j][1] += av * w0.y;
        acc[j][2] += av * w0.z; acc[j][3] += av * w0.w;
        acc[j][4] += av * w1.x; acc[j][5] += av * w1.y;
        acc[j][6] += av * w1.z; acc[j][7] += av * w1.w;
      }
    }
  }
  const int p0 = cc >> 5;          // cols cc..cc+3 -> panel 0/1
  const int pc0 = cc & 31;
  #pragma unroll
  for (int j = 0; j < 8; ++j) {
    int row = r0 + tg + 16 * j;
    if (row < NN) {
      const float dsc = dis[row];
      ushort4 u0, u1;
      u0.x = f2bf(acc[j][0] * dsc); u0.y = f2bf(acc[j][1] * dsc);
      u0.z = f2bf(acc[j][2] * dsc); u0.w = f2bf(acc[j][3] * dsc);
      u1.x = f2bf(acc[j][4] * dsc); u1.y = f2bf(acc[j][5] * dsc);
      u1.z = f2bf(acc[j][6] * dsc); u1.w = f2bf(acc[j][7] * dsc);
      *(ushort4*)&C[(size_t)p0 * PSTRH + (size_t)row * CPW + pc0] = u0;
      *(ushort4*)&C[(size_t)(p0 + 2) * PSTRH + (size_t)row * CPW + pc0] = u1;
    }
  }
}

// ---------------- CSR gather-aggregate (bf16 panels, window-sorted) ---------------
// thread = (node, 8 cols). Wave = 16 degree-adjacent nodes from one 1024-node
// window. Per edge: one 16 B uint4 gather; node's 4 threads together = one 64 B
// line. Segments 4-padded with dummy row NN (zeros). chunk = bid&3.
__device__ __forceinline__ void bacc(float* a, uint4 q) {
  union { unsigned int u; float f; } t;
  t.u = q.x << 16;          a[0] += t.f;
  t.u = q.x & 0xFFFF0000u;  a[1] += t.f;
  t.u = q.y << 16;          a[2] += t.f;
  t.u = q.y & 0xFFFF0000u;  a[3] += t.f;
  t.u = q.z << 16;          a[4] += t.f;
  t.u = q.z & 0xFFFF0000u;  a[5] += t.f;
  t.u = q.w << 16;          a[6] += t.f;
  t.u = q.w & 0xFFFF0000u;  a[7] += t.f;
}

__global__ __launch_bounds__(256) void k_agg(const unsigned short* __restrict__ Tpanels,
                                             const float* __restrict__ dis,
                                             const int* __restrict__ row_start,
                                             const int* __restrict__ csr_src,
                                             const int* __restrict__ perm,
                                             const float* __restrict__ bias,
                                             float* __restrict__ out) {
  const int tid = threadIdx.x;
  const int chunk = blockIdx.x & (NCH - 1);
  const int idx = (blockIdx.x >> 2) * 64 + (tid >> 2);
  if (idx >= NN) return;
  const int n = perm[idx];
  const int c8 = tid & 3;                       // 8-col slot within chunk
  const unsigned short* __restrict__ P = Tpanels + (size_t)chunk * PSTRH;
  const int4* __restrict__ csr4 = (const int4*)csr_src;

  const int jb = row_start[n] >> 2, je = row_start[n + 1] >> 2;   // 4-aligned
  float a0[8] = {0,0,0,0,0,0,0,0};
  float a1[8] = {0,0,0,0,0,0,0,0};
  int j = jb;
  for (; j + 2 <= je; j += 2) {
    int4 sA = csr4[j], sB = csr4[j + 1];
    uint4 q0 = *(const uint4*)&P[(size_t)sA.x * CPW + c8 * 8];
    uint4 q1 = *(const uint4*)&P[(size_t)sA.y * CPW + c8 * 8];
    uint4 q2 = *(const uint4*)&P[(size_t)sA.z * CPW + c8 * 8];
    uint4 q3 = *(const uint4*)&P[(size_t)sA.w * CPW + c8 * 8];
    uint4 q4 = *(const uint4*)&P[(size_t)sB.x * CPW + c8 * 8];
    uint4 q5 = *(const uint4*)&P[(size_t)sB.y * CPW + c8 * 8];
    uint4 q6 = *(const uint4*)&P[(size_t)sB.z * CPW + c8 * 8];
    uint4 q7 = *(const uint4*)&P[(size_t)sB.w * CPW + c8 * 8];
    bacc(a0, q0); bacc(a1, q1); bacc(a0, q2); bacc(a1, q3);
    bacc(a0, q4); bacc(a1, q5); bacc(a0, q6); bacc(a1, q7);
  }
  if (j < je) {
    int4 sA = csr4[j];
    uint4 q0 = *(const uint4*)&P[(size_t)sA.x * CPW + c8 * 8];
    uint4 q1 = *(const uint4*)&P[(size_t)sA.y * CPW + c8 * 8];
    uint4 q2 = *(const uint4*)&P[(size_t)sA.z * CPW + c8 * 8];
    uint4 q3 = *(const uint4*)&P[(size_t)sA.w * CPW + c8 * 8];
    bacc(a0, q0); bacc(a1, q1); bacc(a0, q2); bacc(a1, q3);
  }
  const float dn = dis[n];
  const int cb = chunk * CPW + c8 * 8;
  const float4 b0 = *(const float4*)&bias[cb];
  const float4 b1 = *(const float4*)&bias[cb + 4];
  float r[8];
  #pragma unroll
  for (int i = 0; i < 8; ++i) r[i] = (a0[i] + a1[i]) * dn;
  r[0] += b0.x; r[1] += b0.y; r[2] += b0.z; r[3] += b0.w;
  r[4] += b1.x; r[5] += b1.y; r[6] += b1.z; r[7] += b1.w;
  #pragma unroll
  for (int i = 0; i < 8; ++i) r[i] = (r[i] >= 0.f) ? r[i] : 0.01f * r[i];
  float* o = out + (size_t)n * HD + cb;
  *(float4*)o = make_float4(r[0], r[1], r[2], r[3]);
  *(float4*)(o + 4) = make_float4(r[4], r[5], r[6], r[7]);
}

extern "C" void kernel_launch(void* const* d_in, const int* in_sizes, int n_in,
                              void* d_out, int out_size, void* d_ws, size_t ws_size,
                              hipStream_t stream) {
  const float* x  = (const float*)d_in[0];
  const int*   ei = (const int*)d_in[1];
  const float* W0 = (const float*)d_in[2];
  const float* b0 = (const float*)d_in[3];
  const float* W1 = (const float*)d_in[4];
  const float* b1 = (const float*)d_in[5];
  float* out = (float*)d_out;
  const int* src = ei;        // edge_index[0] = message source
  const int* dst = ei + NE;   // edge_index[1] = aggregation target

  char* p = (char*)d_ws;
  int*   deg       = (int*)p;    p += 50048 * 4;
  float* dis       = (float*)p;  p += 50048 * 4;
  int*   row_start = (int*)p;    p += 50052 * 4;
  int*   cursor    = (int*)p;    p += 50048 * 4;
  int*   partial   = (int*)p;    p += 256 * 4;
  int*   perm      = (int*)p;    p += 50048 * 4;
  int*   csr       = (int*)p;    p += 1000064 * 4;   // padded: <= 850000 + 3*50000
  unsigned short* bufA = (unsigned short*)p;  // 4 panels x 1600032 halves (~12.8 MB)
  // sort scratch aliases bufA head (dead until first GEMM; dummy rows live at tail)
  int*   hist2     = (int*)bufA;          // 12544
  int*   partial2  = hist2 + NH2;         // 49

  // graph build (once, reused by both layers)
  k_init_deg<<<196, 256, 0, stream>>>(deg);
  k_count<<<3125, 256, 0, stream>>>(dst, deg);
  k_blocksum_pad<<<NB, 256, 0, stream>>>(deg, partial);
  k_scanp<<<1, 256, 0, stream>>>(partial, NB);
  k_scatter<<<NB, 256, 0, stream>>>(deg, partial, row_start, cursor, dis);
  k_fill<<<(EH + 255) / 256, 256, 0, stream>>>(src, dst, cursor, csr);
  k_pad<<<NB, 256, 0, stream>>>(deg, row_start, csr);

  // windowed degree counting-sort -> perm (+ dummy-row zeroing in k_hist2)
  hipMemsetAsync(hist2, 0, NH2 * 4, stream);
  k_hist2<<<196, 256, 0, stream>>>(deg, hist2, bufA);
  k_blocksum<<<NH2B, 256, 0, stream>>>(hist2, partial2, NH2);
  k_scanp<<<1, 256, 0, stream>>>(partial2, NH2B);
  k_excl<<<NH2B, 256, 0, stream>>>(hist2, partial2, NH2);
  k_perm2<<<196, 256, 0, stream>>>(deg, hist2, perm);

  const int AGG_GRID = NCH * ((NN + 63) / 64);   // 4 * 782 = 3128 blocks
  // layer 1
  k_gemm<<<(NN + GR - 1) / GR, 256, 0, stream>>>(x, W0, dis, bufA);
  k_agg<<<AGG_GRID, 256, 0, stream>>>(bufA, dis, row_start, csr, perm, b0, out);
  // layer 2
  k_gemm<<<(NN + GR - 1) / GR, 256, 0, stream>>>(out, W1, dis, bufA);
  k_agg<<<AGG_GRID, 256, 0, stream>>>(bufA, dis, row_start, csr, perm, b1, out);
}